// Round 4
// baseline (190.900 us; speedup 1.0000x reference)
//
#include <hip/hip_runtime.h>

// SparseDopplerAttention on gfx950 — R4.
// Identity: out[q] = (sum_k P[q,k]*vsum[k]) / (sum_k P[q,k]) + sum_d bv[d],
//   vsum[k] = x[k] . colsum(Wv)   (fp32) — V GEMM and PV GEMM eliminated (R3).
// R4: max TLP. 512 blocks x 1024 thr = 2 blocks/CU = 32 waves/CU (8/SIMD, HW max).
// Block (range, half): builds full 512-key K (bf16 LDS, swizzled) + vsum,
// attends 256 queries (16/wave). K-build duplication is cheap (24 MFMA/wave).
// VGPR must stay <=64 for 8 waves/SIMD: launch_bounds(1024,8) pins it.

#define SCALE 0.18033688011112042f   // log2(e)/8

typedef __bf16 bf16;
typedef bf16 v4bf __attribute__((ext_vector_type(4)));
typedef bf16 v8bf __attribute__((ext_vector_type(8)));
typedef float v4f __attribute__((ext_vector_type(4)));

__device__ __forceinline__ v8bf pk8(float4 a, float4 b) {
    v8bf r;
    r[0] = (bf16)a.x; r[1] = (bf16)a.y; r[2] = (bf16)a.z; r[3] = (bf16)a.w;
    r[4] = (bf16)b.x; r[5] = (bf16)b.y; r[6] = (bf16)b.z; r[7] = (bf16)b.w;
    return r;
}
__device__ __forceinline__ float d4(float4 a, v4f w) {
    return a.x * w[0] + a.y * w[1] + a.z * w[2] + a.w * w[3];
}

__global__ __launch_bounds__(1024, 8)
void sda_kernel(const float* __restrict__ power,
                const int*   __restrict__ ele_i,
                const int*   __restrict__ azi_i,
                const float* __restrict__ ele_t,
                const float* __restrict__ azi_t,
                const float* __restrict__ Wq, const float* __restrict__ bq,
                const float* __restrict__ Wk, const float* __restrict__ bk,
                const float* __restrict__ Wv, const float* __restrict__ bv,
                float* __restrict__ out)
{
    extern __shared__ char smem[];
    char*  Kb   = smem;                      // 64 KB: K [key][dim] bf16, 128 B rows, blk16 ^= key&7
    float* vsum = (float*)(smem + 65536);    // 512 f32
    float* wvs  = (float*)(smem + 67584);    // 96 f32 colsums of Wv
    float* wvp  = (float*)Kb;                // transient [8][96] partials (dead before K writes)

    const int tid  = threadIdx.x;
    const int wave = tid >> 6;
    const int lane = tid & 63;
    const int l15  = lane & 15;
    const int quad = lane >> 4;
    const int range = blockIdx.x >> 1;
    const int half  = blockIdx.x & 1;
    const int krow0 = range * 512 + wave * 32;               // this wave's K/vsum rows
    const int qrow0 = range * 512 + half * 256 + wave * 16;  // this wave's 16 queries

    // ---- bvs = sum(bv), per-wave shuffle reduce (constant, added at the very end) ----
    float bvs = bv[lane];
#pragma unroll
    for (int d = 1; d < 64; d <<= 1) bvs += __shfl_xor(bvs, d);

    // ---- colsum(Wv): 768 threads x 8 rows -> partials -> 96-thread reduce ----
    if (tid < 768) {
        int grp = tid / 96, col = tid - grp * 96;
        const float* p = Wv + grp * 8 * 96 + col;
        float s = 0.f;
#pragma unroll
        for (int r = 0; r < 8; r++) s += p[r * 96];
        wvp[grp * 96 + col] = s;
    }
    __syncthreads();
    if (tid < 96) {
        float s = 0.f;
#pragma unroll
        for (int g = 0; g < 8; g++) s += wvp[g * 96 + tid];
        wvs[tid] = s;
    }
    __syncthreads();

    // per-lane wvs slice (feat layout: [0:32)+[32:64) power, [64:96) embeds)
    v4f w0 = *(const v4f*)(wvs + quad * 8);
    v4f w1 = *(const v4f*)(wvs + quad * 8 + 4);
    v4f w2 = *(const v4f*)(wvs + 32 + quad * 8);
    v4f w3 = *(const v4f*)(wvs + 32 + quad * 8 + 4);
    v4f w4 = *(const v4f*)(wvs + 64 + quad * 8);
    v4f w5 = *(const v4f*)(wvs + 64 + quad * 8 + 4);

    // ---- x fragments for K rows (bf16) + fp32 vsum ----
    v8bf xa[2][3];
#pragma unroll
    for (int mt = 0; mt < 2; mt++) {
        int row = krow0 + mt * 16 + l15;
        const float* pr = power + (size_t)row * 64;
        float4 a0 = *(const float4*)(pr + quad * 8);
        float4 a1 = *(const float4*)(pr + quad * 8 + 4);
        float4 a2 = *(const float4*)(pr + 32 + quad * 8);
        float4 a3 = *(const float4*)(pr + 32 + quad * 8 + 4);
        int ie = ele_i[row];
        int ia = azi_i[row];
        const float* tb = (quad < 2) ? (ele_t + ie * 16 + quad * 8)
                                     : (azi_t + ia * 16 + (quad - 2) * 8);
        float4 a4 = *(const float4*)tb;
        float4 a5 = *(const float4*)(tb + 4);
        xa[mt][0] = pk8(a0, a1);
        xa[mt][1] = pk8(a2, a3);
        xa[mt][2] = pk8(a4, a5);
        float dd = d4(a0, w0) + d4(a1, w1) + d4(a2, w2) + d4(a3, w3) + d4(a4, w4) + d4(a5, w5);
        dd += __shfl_xor(dd, 16);
        dd += __shfl_xor(dd, 32);
        if (quad == 0) vsum[wave * 32 + mt * 16 + l15] = dd;
    }

    // ---- Q^T = Wq @ xq^T for this wave's 16 queries, fold SCALE, LDS transpose ----
    v8bf qf[2];
    {
        v8bf xq[3];
        {
            int row = qrow0 + l15;
            const float* pr = power + (size_t)row * 64;
            float4 a0 = *(const float4*)(pr + quad * 8);
            float4 a1 = *(const float4*)(pr + quad * 8 + 4);
            float4 a2 = *(const float4*)(pr + 32 + quad * 8);
            float4 a3 = *(const float4*)(pr + 32 + quad * 8 + 4);
            int ie = ele_i[row];
            int ia = azi_i[row];
            const float* tb = (quad < 2) ? (ele_t + ie * 16 + quad * 8)
                                         : (azi_t + ia * 16 + (quad - 2) * 8);
            xq[0] = pk8(a0, a1);
            xq[1] = pk8(a2, a3);
            xq[2] = pk8(*(const float4*)tb, *(const float4*)(tb + 4));
        }
        char* Sw = Kb + wave * 4096;   // wave's own K region; scratch before K write
#pragma unroll
        for (int mtd = 0; mtd < 4; mtd++) {
            v8bf wq3[3];
#pragma unroll
            for (int kt = 0; kt < 3; kt++) {
                const float* p = Wq + (mtd * 16 + l15) * 96 + kt * 32 + quad * 8;
                wq3[kt] = pk8(*(const float4*)p, *(const float4*)(p + 4));
            }
            float4 bq4 = *(const float4*)(bq + mtd * 16 + quad * 4);
            v4f acc = {0.f, 0.f, 0.f, 0.f};
#pragma unroll
            for (int kt = 0; kt < 3; kt++)
                acc = __builtin_amdgcn_mfma_f32_16x16x32_bf16(wq3[kt], xq[kt], acc, 0, 0, 0);
            v4bf o;
            o[0] = (bf16)((acc[0] + bq4.x) * SCALE);
            o[1] = (bf16)((acc[1] + bq4.y) * SCALE);
            o[2] = (bf16)((acc[2] + bq4.z) * SCALE);
            o[3] = (bf16)((acc[3] + bq4.w) * SCALE);
            *(v4bf*)(Sw + l15 * 128 +
                     ((((mtd * 2 + (quad >> 1)) ^ (l15 & 7)) << 4) | ((quad & 1) << 3))) = o;
        }
#pragma unroll
        for (int kt = 0; kt < 2; kt++)
            qf[kt] = *(const v8bf*)(Sw + l15 * 128 + (((kt * 4 + quad) ^ (l15 & 7)) << 4));
    }

    // ---- K^T = Wk @ xa^T, overwrite scratch (same-wave DS ops in order) ----
#pragma unroll
    for (int mtd = 0; mtd < 4; mtd++) {
        v8bf wk3[3];
#pragma unroll
        for (int kt = 0; kt < 3; kt++) {
            const float* p = Wk + (mtd * 16 + l15) * 96 + kt * 32 + quad * 8;
            wk3[kt] = pk8(*(const float4*)p, *(const float4*)(p + 4));
        }
        float4 bk4 = *(const float4*)(bk + mtd * 16 + quad * 4);
#pragma unroll
        for (int ntr = 0; ntr < 2; ntr++) {
            v4f acc = {0.f, 0.f, 0.f, 0.f};
#pragma unroll
            for (int kt = 0; kt < 3; kt++)
                acc = __builtin_amdgcn_mfma_f32_16x16x32_bf16(wk3[kt], xa[ntr][kt], acc, 0, 0, 0);
            int keyb = wave * 32 + ntr * 16 + l15;
            v4bf o;
            o[0] = (bf16)(acc[0] + bk4.x);
            o[1] = (bf16)(acc[1] + bk4.y);
            o[2] = (bf16)(acc[2] + bk4.z);
            o[3] = (bf16)(acc[3] + bk4.w);
            *(v4bf*)(Kb + keyb * 128 +
                     ((((mtd * 2 + (quad >> 1)) ^ (keyb & 7)) << 4) | ((quad & 1) << 3))) = o;
        }
    }
    __syncthreads();

    // ---- Phase B: S^T = K @ Q^T (log2 domain), exp2, weighted accumulate ----
    float osum = 0.f, lsum = 0.f;
#pragma unroll 2
    for (int t = 0; t < 16; t++) {
        v8bf kf[2][2];
#pragma unroll
        for (int mtk = 0; mtk < 2; mtk++)
#pragma unroll
            for (int kt = 0; kt < 2; kt++) {
                int key = t * 32 + mtk * 16 + l15;
                kf[mtk][kt] = *(const v8bf*)(Kb + key * 128 + (((kt * 4 + quad) ^ (key & 7)) << 4));
            }
        v4f vs[2];
#pragma unroll
        for (int mtk = 0; mtk < 2; mtk++)
            vs[mtk] = *(const v4f*)(vsum + t * 32 + mtk * 16 + quad * 4);
#pragma unroll
        for (int mtk = 0; mtk < 2; mtk++) {
            v4f acc = {0.f, 0.f, 0.f, 0.f};
            acc = __builtin_amdgcn_mfma_f32_16x16x32_bf16(kf[mtk][0], qf[0], acc, 0, 0, 0);
            acc = __builtin_amdgcn_mfma_f32_16x16x32_bf16(kf[mtk][1], qf[1], acc, 0, 0, 0);
            float p0 = __builtin_amdgcn_exp2f(acc[0]);
            float p1 = __builtin_amdgcn_exp2f(acc[1]);
            float p2 = __builtin_amdgcn_exp2f(acc[2]);
            float p3 = __builtin_amdgcn_exp2f(acc[3]);
            lsum += (p0 + p1) + (p2 + p3);
            osum += ((p0 * vs[mtk][0] + p1 * vs[mtk][1]) +
                     (p2 * vs[mtk][2] + p3 * vs[mtk][3]));
        }
    }

    // ---- epilogue: reduce over key-quads; bvs re-added outside the softmax ----
    float lv = lsum;
    lv += __shfl_xor(lv, 16);
    lv += __shfl_xor(lv, 32);
    float ov = osum;
    ov += __shfl_xor(ov, 16);
    ov += __shfl_xor(ov, 32);
    if (quad == 0) out[qrow0 + l15] = ov / lv + bvs;
}

extern "C" void kernel_launch(void* const* d_in, const int* in_sizes, int n_in,
                              void* d_out, int out_size, void* d_ws, size_t ws_size,
                              hipStream_t stream) {
    const float* power = (const float*)d_in[0];
    const int*   ele_i = (const int*)d_in[1];
    // d_in[2] = range_indices: unused by the reference (positional reshape)
    const int*   azi_i = (const int*)d_in[3];
    const float* ele_t = (const float*)d_in[4];
    const float* azi_t = (const float*)d_in[5];
    const float* Wq = (const float*)d_in[6];
    const float* bq = (const float*)d_in[7];
    const float* Wk = (const float*)d_in[8];
    const float* bk = (const float*)d_in[9];
    const float* Wv = (const float*)d_in[10];
    const float* bv = (const float*)d_in[11];
    float* out = (float*)d_out;

    const int lds_bytes = 65536 + 2048 + 512;   // Kb + vsum + wvs
    (void)hipFuncSetAttribute(reinterpret_cast<const void*>(sda_kernel),
                              hipFuncAttributeMaxDynamicSharedMemorySize, lds_bytes);
    sda_kernel<<<512, 1024, lds_bytes, stream>>>(power, ele_i, azi_i, ele_t, azi_t,
                                                 Wq, bq, Wk, bk, Wv, bv, out);
}

// Round 5
// 168.352 us; speedup vs baseline: 1.1339x; 1.1339x over previous
//
#include <hip/hip_runtime.h>

// SparseDopplerAttention on gfx950 — R5.
// Identity (R3): out[q] = (sum_k P[q,k]*vsum[k]) / (sum_k P[q,k]) + sum(bv),
//   vsum[k] = x[k] . colsum(Wv)  in fp32 — V GEMM and PV GEMM eliminated.
// R5: 512 blocks x 1024 thr, LDS 68 KB -> 2 blocks/CU IF VGPR <= 64.
// No hard VGPR cap (R4's launch_bounds(1024,8) spilled 230 MB of scratch);
// instead pressure is reduced structurally:
//   - wave w of half h attends queries w*32+h*16..+15 == its own xa[half] rows,
//     so the Q-GEMM B-operand is xa[half] (no separate query x load),
//   - wq/wk fragments JIT-loaded per dim-tile, colsum slices streamed from LDS.

#define SCALE 0.18033688011112042f   // log2(e)/8

typedef __bf16 bf16;
typedef bf16 v4bf __attribute__((ext_vector_type(4)));
typedef bf16 v8bf __attribute__((ext_vector_type(8)));
typedef float v4f __attribute__((ext_vector_type(4)));

__device__ __forceinline__ v8bf pk8(float4 a, float4 b) {
    v8bf r;
    r[0] = (bf16)a.x; r[1] = (bf16)a.y; r[2] = (bf16)a.z; r[3] = (bf16)a.w;
    r[4] = (bf16)b.x; r[5] = (bf16)b.y; r[6] = (bf16)b.z; r[7] = (bf16)b.w;
    return r;
}
__device__ __forceinline__ float d4(float4 a, const float* w) {
    return a.x * w[0] + a.y * w[1] + a.z * w[2] + a.w * w[3];
}

__global__ __launch_bounds__(1024, 4)
void sda_kernel(const float* __restrict__ power,
                const int*   __restrict__ ele_i,
                const int*   __restrict__ azi_i,
                const float* __restrict__ ele_t,
                const float* __restrict__ azi_t,
                const float* __restrict__ Wq, const float* __restrict__ bq,
                const float* __restrict__ Wk, const float* __restrict__ bk,
                const float* __restrict__ Wv, const float* __restrict__ bv,
                float* __restrict__ out)
{
    extern __shared__ char smem[];
    char*  Kb   = smem;                      // 64 KB: K [key][dim] bf16, 128 B rows, blk16 ^= key&7
    float* vsum = (float*)(smem + 65536);    // 512 f32
    float* wvs  = (float*)(smem + 67584);    // 96 f32 colsums of Wv
    float* wvp  = (float*)Kb;                // transient [8][96] partials (dead before K writes)

    const int tid  = threadIdx.x;
    const int wave = tid >> 6;
    const int lane = tid & 63;
    const int l15  = lane & 15;
    const int quad = lane >> 4;
    const int range = blockIdx.x >> 1;
    const int half  = blockIdx.x & 1;
    const int krow0 = range * 512 + wave * 32;        // this wave's x/K/vsum rows
    const int qrow0 = krow0 + half * 16;              // this wave's 16 queries (own rows!)

    // ---- bvs = sum(bv), per-wave shuffle reduce (added after the softmax avg) ----
    float bvs = bv[lane];
#pragma unroll
    for (int d = 1; d < 64; d <<= 1) bvs += __shfl_xor(bvs, d);

    // ---- colsum(Wv): 768 threads x 8 rows -> partials -> 96-thread reduce ----
    if (tid < 768) {
        int grp = tid / 96, col = tid - grp * 96;
        const float* p = Wv + grp * 8 * 96 + col;
        float s = 0.f;
#pragma unroll
        for (int r = 0; r < 8; r++) s += p[r * 96];
        wvp[grp * 96 + col] = s;
    }
    __syncthreads();
    if (tid < 96) {
        float s = 0.f;
#pragma unroll
        for (int g = 0; g < 8; g++) s += wvp[g * 96 + tid];
        wvs[tid] = s;
    }
    __syncthreads();

    // ---- x fragments for this wave's 32 rows (bf16) + fp32 vsum ----
    v8bf xa[2][3];
#pragma unroll
    for (int mt = 0; mt < 2; mt++) {
        int row = krow0 + mt * 16 + l15;
        const float* pr = power + (size_t)row * 64;
        float4 a0 = *(const float4*)(pr + quad * 8);
        float4 a1 = *(const float4*)(pr + quad * 8 + 4);
        float dd = d4(a0, wvs + quad * 8) + d4(a1, wvs + quad * 8 + 4);
        xa[mt][0] = pk8(a0, a1);
        a0 = *(const float4*)(pr + 32 + quad * 8);
        a1 = *(const float4*)(pr + 32 + quad * 8 + 4);
        dd += d4(a0, wvs + 32 + quad * 8) + d4(a1, wvs + 32 + quad * 8 + 4);
        xa[mt][1] = pk8(a0, a1);
        int ie = ele_i[row];
        int ia = azi_i[row];
        const float* tb = (quad < 2) ? (ele_t + ie * 16 + quad * 8)
                                     : (azi_t + ia * 16 + (quad - 2) * 8);
        a0 = *(const float4*)tb;
        a1 = *(const float4*)(tb + 4);
        dd += d4(a0, wvs + 64 + quad * 8) + d4(a1, wvs + 64 + quad * 8 + 4);
        xa[mt][2] = pk8(a0, a1);
        dd += __shfl_xor(dd, 16);
        dd += __shfl_xor(dd, 32);
        if (quad == 0) vsum[wave * 32 + mt * 16 + l15] = dd;
    }

    // ---- Q^T = Wq @ xa[half]^T (queries are the wave's own rows), LDS transpose ----
    char* Sw = Kb + wave * 4096;   // wave's own K region; scratch before K write
#pragma unroll
    for (int mtd = 0; mtd < 4; mtd++) {
        v4f acc = {0.f, 0.f, 0.f, 0.f};
#pragma unroll
        for (int kt = 0; kt < 3; kt++) {
            const float* p = Wq + (mtd * 16 + l15) * 96 + kt * 32 + quad * 8;
            v8bf wq = pk8(*(const float4*)p, *(const float4*)(p + 4));
            acc = __builtin_amdgcn_mfma_f32_16x16x32_bf16(wq, xa[half][kt], acc, 0, 0, 0);
        }
        float4 bq4 = *(const float4*)(bq + mtd * 16 + quad * 4);
        v4bf o;
        o[0] = (bf16)((acc[0] + bq4.x) * SCALE);
        o[1] = (bf16)((acc[1] + bq4.y) * SCALE);
        o[2] = (bf16)((acc[2] + bq4.z) * SCALE);
        o[3] = (bf16)((acc[3] + bq4.w) * SCALE);
        *(v4bf*)(Sw + l15 * 128 +
                 ((((mtd * 2 + (quad >> 1)) ^ (l15 & 7)) << 4) | ((quad & 1) << 3))) = o;
    }
    v8bf qf[2];
#pragma unroll
    for (int kt = 0; kt < 2; kt++)
        qf[kt] = *(const v8bf*)(Sw + l15 * 128 + (((kt * 4 + quad) ^ (l15 & 7)) << 4));

    // ---- K^T = Wk @ xa^T, overwrite scratch (same-wave DS ops in order) ----
#pragma unroll
    for (int mtd = 0; mtd < 4; mtd++) {
        v4f acc0 = {0.f, 0.f, 0.f, 0.f};
        v4f acc1 = {0.f, 0.f, 0.f, 0.f};
#pragma unroll
        for (int kt = 0; kt < 3; kt++) {
            const float* p = Wk + (mtd * 16 + l15) * 96 + kt * 32 + quad * 8;
            v8bf wk = pk8(*(const float4*)p, *(const float4*)(p + 4));
            acc0 = __builtin_amdgcn_mfma_f32_16x16x32_bf16(wk, xa[0][kt], acc0, 0, 0, 0);
            acc1 = __builtin_amdgcn_mfma_f32_16x16x32_bf16(wk, xa[1][kt], acc1, 0, 0, 0);
        }
        float4 bk4 = *(const float4*)(bk + mtd * 16 + quad * 4);
#pragma unroll
        for (int ntr = 0; ntr < 2; ntr++) {
            v4f acc = ntr ? acc1 : acc0;
            int keyb = wave * 32 + ntr * 16 + l15;
            v4bf o;
            o[0] = (bf16)(acc[0] + bk4.x);
            o[1] = (bf16)(acc[1] + bk4.y);
            o[2] = (bf16)(acc[2] + bk4.z);
            o[3] = (bf16)(acc[3] + bk4.w);
            *(v4bf*)(Kb + keyb * 128 +
                     ((((mtd * 2 + (quad >> 1)) ^ (keyb & 7)) << 4) | ((quad & 1) << 3))) = o;
        }
    }
    __syncthreads();

    // ---- Phase B: S^T = K @ Q^T (log2 domain), exp2, weighted accumulate ----
    float osum = 0.f, lsum = 0.f;
#pragma unroll 2
    for (int t = 0; t < 16; t++) {
        v8bf kf[2][2];
#pragma unroll
        for (int mtk = 0; mtk < 2; mtk++)
#pragma unroll
            for (int kt = 0; kt < 2; kt++) {
                int key = t * 32 + mtk * 16 + l15;
                kf[mtk][kt] = *(const v8bf*)(Kb + key * 128 + (((kt * 4 + quad) ^ (key & 7)) << 4));
            }
        v4f vs[2];
#pragma unroll
        for (int mtk = 0; mtk < 2; mtk++)
            vs[mtk] = *(const v4f*)(vsum + t * 32 + mtk * 16 + quad * 4);
#pragma unroll
        for (int mtk = 0; mtk < 2; mtk++) {
            v4f acc = {0.f, 0.f, 0.f, 0.f};
            acc = __builtin_amdgcn_mfma_f32_16x16x32_bf16(kf[mtk][0], qf[0], acc, 0, 0, 0);
            acc = __builtin_amdgcn_mfma_f32_16x16x32_bf16(kf[mtk][1], qf[1], acc, 0, 0, 0);
            float p0 = __builtin_amdgcn_exp2f(acc[0]);
            float p1 = __builtin_amdgcn_exp2f(acc[1]);
            float p2 = __builtin_amdgcn_exp2f(acc[2]);
            float p3 = __builtin_amdgcn_exp2f(acc[3]);
            lsum += (p0 + p1) + (p2 + p3);
            osum += ((p0 * vs[mtk][0] + p1 * vs[mtk][1]) +
                     (p2 * vs[mtk][2] + p3 * vs[mtk][3]));
        }
    }

    // ---- epilogue: reduce over key-quads; bvs added outside the softmax ----
    float lv = lsum;
    lv += __shfl_xor(lv, 16);
    lv += __shfl_xor(lv, 32);
    float ov = osum;
    ov += __shfl_xor(ov, 16);
    ov += __shfl_xor(ov, 32);
    if (quad == 0) out[qrow0 + l15] = ov / lv + bvs;
}

extern "C" void kernel_launch(void* const* d_in, const int* in_sizes, int n_in,
                              void* d_out, int out_size, void* d_ws, size_t ws_size,
                              hipStream_t stream) {
    const float* power = (const float*)d_in[0];
    const int*   ele_i = (const int*)d_in[1];
    // d_in[2] = range_indices: unused by the reference (positional reshape)
    const int*   azi_i = (const int*)d_in[3];
    const float* ele_t = (const float*)d_in[4];
    const float* azi_t = (const float*)d_in[5];
    const float* Wq = (const float*)d_in[6];
    const float* bq = (const float*)d_in[7];
    const float* Wk = (const float*)d_in[8];
    const float* bk = (const float*)d_in[9];
    const float* Wv = (const float*)d_in[10];
    const float* bv = (const float*)d_in[11];
    float* out = (float*)d_out;

    const int lds_bytes = 65536 + 2048 + 512;   // Kb + vsum + wvs
    (void)hipFuncSetAttribute(reinterpret_cast<const void*>(sda_kernel),
                              hipFuncAttributeMaxDynamicSharedMemorySize, lds_bytes);
    sda_kernel<<<512, 1024, lds_bytes, stream>>>(power, ele_i, azi_i, ele_t, azi_t,
                                                 Wq, bq, Wk, bk, Wv, bv, out);
}

// Round 6
// 159.168 us; speedup vs baseline: 1.1994x; 1.0577x over previous
//
#include <hip/hip_runtime.h>

// SparseDopplerAttention on gfx950 — R6: two-kernel split.
// Identity (R3, validated): out[q] = (sum_k P[q,k]*vsum[k])/(sum_k P[q,k]) + sum(bv),
//   vsum[k] = x[k].colsum(Wv) in fp32; V GEMM and PV GEMM eliminated.
// R3-R5 lesson: 64 KB shared-K LDS welds occupancy to 1024-thr blocks (cap 16
// waves/CU); the 8-wave/SIMD VGPR gate (<=64 incl AGPR) is unreachable. So:
// K1 (proj): K (bf16, fragment-row-major) + vsum (f32) -> d_ws global.
// K2 (attn): 256-thr blocks, 16 KB LDS, no barriers; streams K/vsum from
// global (L2-resident per XCD via range-major block indexing). Occupancy
// gated only by VGPR -> graceful 6-8 waves/SIMD.

#define SCALE 0.18033688011112042f   // log2(e)/8

typedef __bf16 bf16;
typedef bf16 v4bf __attribute__((ext_vector_type(4)));
typedef bf16 v8bf __attribute__((ext_vector_type(8)));
typedef float v4f __attribute__((ext_vector_type(4)));

__device__ __forceinline__ v8bf pk8(float4 a, float4 b) {
    v8bf r;
    r[0] = (bf16)a.x; r[1] = (bf16)a.y; r[2] = (bf16)a.z; r[3] = (bf16)a.w;
    r[4] = (bf16)b.x; r[5] = (bf16)b.y; r[6] = (bf16)b.z; r[7] = (bf16)b.w;
    return r;
}
__device__ __forceinline__ float d4(float4 a, const float* w) {
    return a.x * w[0] + a.y * w[1] + a.z * w[2] + a.w * w[3];
}

// =================== Kernel 1: K projection + vsum ===================
// 256 blocks x 1024 thr; block = range; wave w owns rows w*32..w*32+31.
// K layout (byte addr within range): key*128 + (dim/8)*16 + (dim%8)*2
//   -> phase-2 b128 read at key*128 + kt*64 + quad*16 is dense.
__global__ __launch_bounds__(1024, 2)
void sda_proj(const float* __restrict__ power,
              const int*   __restrict__ ele_i,
              const int*   __restrict__ azi_i,
              const float* __restrict__ ele_t,
              const float* __restrict__ azi_t,
              const float* __restrict__ Wk, const float* __restrict__ bk,
              const float* __restrict__ Wv,
              char* __restrict__ Kf, float* __restrict__ vsg)
{
    __shared__ float wvp[768];
    __shared__ float wvs[96];

    const int tid  = threadIdx.x;
    const int wave = tid >> 6;
    const int lane = tid & 63;
    const int l15  = lane & 15;
    const int quad = lane >> 4;
    const int range = blockIdx.x;
    const int krow0 = range * 512 + wave * 32;

    // colsum(Wv): 768 threads x 8 rows -> partials -> 96-thread reduce
    if (tid < 768) {
        int grp = tid / 96, col = tid - grp * 96;
        const float* p = Wv + grp * 8 * 96 + col;
        float s = 0.f;
#pragma unroll
        for (int r = 0; r < 8; r++) s += p[r * 96];
        wvp[grp * 96 + col] = s;
    }
    __syncthreads();
    if (tid < 96) {
        float s = 0.f;
#pragma unroll
        for (int g = 0; g < 8; g++) s += wvp[g * 96 + tid];
        wvs[tid] = s;
    }
    __syncthreads();

    // x fragments (bf16) + fp32 vsum for this wave's 32 rows
    v8bf xa[2][3];
#pragma unroll
    for (int mt = 0; mt < 2; mt++) {
        int row = krow0 + mt * 16 + l15;
        const float* pr = power + (size_t)row * 64;
        float4 a0 = *(const float4*)(pr + quad * 8);
        float4 a1 = *(const float4*)(pr + quad * 8 + 4);
        float dd = d4(a0, wvs + quad * 8) + d4(a1, wvs + quad * 8 + 4);
        xa[mt][0] = pk8(a0, a1);
        a0 = *(const float4*)(pr + 32 + quad * 8);
        a1 = *(const float4*)(pr + 32 + quad * 8 + 4);
        dd += d4(a0, wvs + 32 + quad * 8) + d4(a1, wvs + 32 + quad * 8 + 4);
        xa[mt][1] = pk8(a0, a1);
        int ie = ele_i[row];
        int ia = azi_i[row];
        const float* tb = (quad < 2) ? (ele_t + ie * 16 + quad * 8)
                                     : (azi_t + ia * 16 + (quad - 2) * 8);
        a0 = *(const float4*)tb;
        a1 = *(const float4*)(tb + 4);
        dd += d4(a0, wvs + 64 + quad * 8) + d4(a1, wvs + 64 + quad * 8 + 4);
        xa[mt][2] = pk8(a0, a1);
        dd += __shfl_xor(dd, 16);
        dd += __shfl_xor(dd, 32);
        if (quad == 0) vsg[range * 512 + wave * 32 + mt * 16 + l15] = dd;
    }

    // K^T = Wk @ x^T (operand swap: col=l15=key, row=quad*4+r=dim), store b64
    char* kr = Kf + (size_t)range * 65536;
#pragma unroll
    for (int mtd = 0; mtd < 4; mtd++) {
        v4f acc0 = {0.f, 0.f, 0.f, 0.f};
        v4f acc1 = {0.f, 0.f, 0.f, 0.f};
#pragma unroll
        for (int kt = 0; kt < 3; kt++) {
            const float* p = Wk + (mtd * 16 + l15) * 96 + kt * 32 + quad * 8;
            v8bf wk = pk8(*(const float4*)p, *(const float4*)(p + 4));
            acc0 = __builtin_amdgcn_mfma_f32_16x16x32_bf16(wk, xa[0][kt], acc0, 0, 0, 0);
            acc1 = __builtin_amdgcn_mfma_f32_16x16x32_bf16(wk, xa[1][kt], acc1, 0, 0, 0);
        }
        float4 bk4 = *(const float4*)(bk + mtd * 16 + quad * 4);
#pragma unroll
        for (int ntr = 0; ntr < 2; ntr++) {
            v4f acc = ntr ? acc1 : acc0;
            int keyb = wave * 32 + ntr * 16 + l15;
            v4bf o;
            o[0] = (bf16)(acc[0] + bk4.x);
            o[1] = (bf16)(acc[1] + bk4.y);
            o[2] = (bf16)(acc[2] + bk4.z);
            o[3] = (bf16)(acc[3] + bk4.w);
            *(v4bf*)(kr + keyb * 128 + (((mtd * 2 + (quad >> 1)) << 4) | ((quad & 1) << 3))) = o;
        }
    }
}

// =================== Kernel 2: attention ===================
// 1024 blocks x 256 thr; block = qc*256 + range (range-major -> same XCD per
// range under round-robin, K L2-resident). Wave owns 32 queries; no barriers.
__global__ __launch_bounds__(256, 4)
void sda_attn(const float* __restrict__ power,
              const int*   __restrict__ ele_i,
              const int*   __restrict__ azi_i,
              const float* __restrict__ ele_t,
              const float* __restrict__ azi_t,
              const float* __restrict__ Wq, const float* __restrict__ bq,
              const float* __restrict__ bv,
              const char* __restrict__ Kf, const float* __restrict__ vsg,
              float* __restrict__ out)
{
    __shared__ char sq[4][4096];   // per-wave Q-transpose scratch

    const int tid  = threadIdx.x;
    const int wave = tid >> 6;
    const int lane = tid & 63;
    const int l15  = lane & 15;
    const int quad = lane >> 4;
    const int range = blockIdx.x & 255;
    const int qc    = blockIdx.x >> 8;
    const int qrow0 = range * 512 + qc * 128 + wave * 32;

    float bvs = bv[lane];
#pragma unroll
    for (int d = 1; d < 64; d <<= 1) bvs += __shfl_xor(bvs, d);

    // x fragments for this wave's 32 queries
    v8bf xq[2][3];
#pragma unroll
    for (int nt = 0; nt < 2; nt++) {
        int row = qrow0 + nt * 16 + l15;
        const float* pr = power + (size_t)row * 64;
        xq[nt][0] = pk8(*(const float4*)(pr + quad * 8), *(const float4*)(pr + quad * 8 + 4));
        xq[nt][1] = pk8(*(const float4*)(pr + 32 + quad * 8), *(const float4*)(pr + 32 + quad * 8 + 4));
        int ie = ele_i[row];
        int ia = azi_i[row];
        const float* tb = (quad < 2) ? (ele_t + ie * 16 + quad * 8)
                                     : (azi_t + ia * 16 + (quad - 2) * 8);
        xq[nt][2] = pk8(*(const float4*)tb, *(const float4*)(tb + 4));
    }

    // Q^T = Wq @ xq^T, fold SCALE, transpose via own scratch (R3-validated)
    char* Sw = sq[wave];
#pragma unroll
    for (int mtd = 0; mtd < 4; mtd++) {
        v4f acc0 = {0.f, 0.f, 0.f, 0.f};
        v4f acc1 = {0.f, 0.f, 0.f, 0.f};
#pragma unroll
        for (int kt = 0; kt < 3; kt++) {
            const float* p = Wq + (mtd * 16 + l15) * 96 + kt * 32 + quad * 8;
            v8bf wq = pk8(*(const float4*)p, *(const float4*)(p + 4));
            acc0 = __builtin_amdgcn_mfma_f32_16x16x32_bf16(wq, xq[0][kt], acc0, 0, 0, 0);
            acc1 = __builtin_amdgcn_mfma_f32_16x16x32_bf16(wq, xq[1][kt], acc1, 0, 0, 0);
        }
        float4 bq4 = *(const float4*)(bq + mtd * 16 + quad * 4);
#pragma unroll
        for (int nt = 0; nt < 2; nt++) {
            v4f acc = nt ? acc1 : acc0;
            int row = nt * 16 + l15;
            v4bf o;
            o[0] = (bf16)((acc[0] + bq4.x) * SCALE);
            o[1] = (bf16)((acc[1] + bq4.y) * SCALE);
            o[2] = (bf16)((acc[2] + bq4.z) * SCALE);
            o[3] = (bf16)((acc[3] + bq4.w) * SCALE);
            *(v4bf*)(Sw + row * 128 +
                     ((((mtd * 2 + (quad >> 1)) ^ (row & 7)) << 4) | ((quad & 1) << 3))) = o;
        }
    }
    v8bf qf[2][2];
#pragma unroll
    for (int nt = 0; nt < 2; nt++)
#pragma unroll
        for (int kt = 0; kt < 2; kt++)
            qf[nt][kt] = *(const v8bf*)(Sw + (nt * 16 + l15) * 128 +
                                        (((kt * 4 + quad) ^ (l15 & 7)) << 4));

    // Phase B: S^T = K @ Q^T (log2 domain), exp2, weighted accumulate
    const char*  kr  = Kf + (size_t)range * 65536;
    const float* vsr = vsg + range * 512;
    float osum[2] = {0.f, 0.f};
    float lsum[2] = {0.f, 0.f};
#pragma unroll 2
    for (int t = 0; t < 16; t++) {
        v8bf kf[2][2];
#pragma unroll
        for (int mtk = 0; mtk < 2; mtk++)
#pragma unroll
            for (int kt = 0; kt < 2; kt++) {
                int key = t * 32 + mtk * 16 + l15;
                kf[mtk][kt] = *(const v8bf*)(kr + key * 128 + kt * 64 + quad * 16);
            }
        v4f vs[2];
#pragma unroll
        for (int mtk = 0; mtk < 2; mtk++)
            vs[mtk] = *(const v4f*)(vsr + t * 32 + mtk * 16 + quad * 4);
#pragma unroll
        for (int mtk = 0; mtk < 2; mtk++)
#pragma unroll
            for (int nt = 0; nt < 2; nt++) {
                v4f acc = {0.f, 0.f, 0.f, 0.f};
                acc = __builtin_amdgcn_mfma_f32_16x16x32_bf16(kf[mtk][0], qf[nt][0], acc, 0, 0, 0);
                acc = __builtin_amdgcn_mfma_f32_16x16x32_bf16(kf[mtk][1], qf[nt][1], acc, 0, 0, 0);
                float p0 = __builtin_amdgcn_exp2f(acc[0]);
                float p1 = __builtin_amdgcn_exp2f(acc[1]);
                float p2 = __builtin_amdgcn_exp2f(acc[2]);
                float p3 = __builtin_amdgcn_exp2f(acc[3]);
                lsum[nt] += (p0 + p1) + (p2 + p3);
                osum[nt] += ((p0 * vs[mtk][0] + p1 * vs[mtk][1]) +
                             (p2 * vs[mtk][2] + p3 * vs[mtk][3]));
            }
    }

    // epilogue: reduce over key-quads; bvs added outside the softmax
#pragma unroll
    for (int nt = 0; nt < 2; nt++) {
        float lv = lsum[nt];
        lv += __shfl_xor(lv, 16);
        lv += __shfl_xor(lv, 32);
        float ov = osum[nt];
        ov += __shfl_xor(ov, 16);
        ov += __shfl_xor(ov, 32);
        if (quad == 0) out[qrow0 + nt * 16 + l15] = ov / lv + bvs;
    }
}

extern "C" void kernel_launch(void* const* d_in, const int* in_sizes, int n_in,
                              void* d_out, int out_size, void* d_ws, size_t ws_size,
                              hipStream_t stream) {
    const float* power = (const float*)d_in[0];
    const int*   ele_i = (const int*)d_in[1];
    // d_in[2] = range_indices: unused by the reference (positional reshape)
    const int*   azi_i = (const int*)d_in[3];
    const float* ele_t = (const float*)d_in[4];
    const float* azi_t = (const float*)d_in[5];
    const float* Wq = (const float*)d_in[6];
    const float* bq = (const float*)d_in[7];
    const float* Wk = (const float*)d_in[8];
    const float* bk = (const float*)d_in[9];
    const float* Wv = (const float*)d_in[10];
    const float* bv = (const float*)d_in[11];
    float* out = (float*)d_out;

    char*  Kf  = (char*)d_ws;                       // 256 ranges x 64 KB = 16 MB
    float* vsg = (float*)((char*)d_ws + 16777216);  // 256 x 512 f32 = 512 KB

    sda_proj<<<256, 1024, 0, stream>>>(power, ele_i, azi_i, ele_t, azi_t,
                                       Wk, bk, Wv, Kf, vsg);
    sda_attn<<<1024, 256, 0, stream>>>(power, ele_i, azi_i, ele_t, azi_t,
                                       Wq, bq, bv, Kf, vsg, out);
}